// Round 5
// baseline (619.142 us; speedup 1.0000x reference)
//
#include <hip/hip_runtime.h>
#include <hip/hip_bf16.h>
#include <math.h>

#define N_NODES 4096
#define F_INN   256
#define F_OUTT  64
#define HID     64
#define MAXDEG  64

// Scratch in device globals (no ws_size dependence). Fully rewritten each call.
__device__ int    g_mode;                    // 0 = fp32 inputs, 1 = bf16 inputs
__device__ float  g_Wh [N_NODES * F_OUTT];
__device__ float  g_s1 [N_NODES];
__device__ float  g_s2 [N_NODES];
__device__ int    g_rev[N_NODES * MAXDEG];
__device__ int    g_perm[N_NODES];
__device__ float4 g_GX [N_NODES * F_OUTT];   // per (node, unit): quad {i,f,g,o}

__device__ __forceinline__ float bf2f(unsigned short u) {
  union { unsigned int i; float f; } v; v.i = ((unsigned int)u) << 16; return v.f;
}

__device__ __forceinline__ float bcastf(float v, int l) {
#if __has_builtin(__builtin_amdgcn_readlane)
  return __int_as_float(__builtin_amdgcn_readlane(__float_as_int(v), l));
#else
  return __shfl(v, l);
#endif
}

__device__ __forceinline__ float sigm(float x) { return 1.f / (1.f + __expf(-x)); }
__device__ __forceinline__ float tanh_fast(float x) { return 1.f - 2.f / (1.f + __expf(2.f * x)); }

// S0: setup = dtype detect + counting sort by seq_length descending.
// fp32 adj words are exactly 0x00000000/0x3F800000 (low16 always 0);
// bf16 adj has ~500 nonzero low-halves in the first 65536 words.
__global__ __launch_bounds__(256) void k_setup(
    const unsigned int* __restrict__ aw, const int* __restrict__ seq)
{
  __shared__ int any;
  __shared__ int hist[MAXDEG + 1];
  __shared__ int offs[MAXDEG + 1];
  const int tid = threadIdx.x;
  if (tid == 0) any = 0;
  if (tid <= MAXDEG) hist[tid] = 0;
  __syncthreads();
  int loc = 0;
  for (int i = tid; i < 65536; i += 256)
    loc |= ((aw[i] & 0xFFFFu) != 0u) ? 1 : 0;
  if (loc) atomicOr(&any, 1);
  for (int i = tid; i < N_NODES; i += 256)
    atomicAdd(&hist[min(max(seq[i], 0), MAXDEG)], 1);
  __syncthreads();
  if (tid == 0) {
    g_mode = any ? 1 : 0;
    int run = 0;
    for (int L = MAXDEG; L >= 0; L--) { offs[L] = run; run += hist[L]; }
  }
  __syncthreads();
  for (int i = tid; i < N_NODES; i += 256) {
    int p = atomicAdd(&offs[min(max(seq[i], 0), MAXDEG)], 1);
    g_perm[p] = i;
  }
}

// K1: Wh = h @ W (fp64 accumulate -> fp32), s1 = Wh@a1, s2 = Wh@a2 (fp64).
// h row held in registers (float4/lane) and broadcast via readlane;
// W staged in LDS [k][d] (b32 reads, 2-way bank alias = free).
// Accumulation order k ascending — bit-identical to round 4.
__global__ __launch_bounds__(256) void k_wh(
    const void* __restrict__ h, const void* __restrict__ W, const void* __restrict__ a)
{
  const bool bf16 = (g_mode == 1);
  __shared__ float Ws[F_INN * F_OUTT];   // 64 KB
  const int tid = threadIdx.x;
  if (bf16) {
    const unsigned short* Wu = (const unsigned short*)W;
    for (int idx = tid; idx < F_INN * F_OUTT; idx += 256) Ws[idx] = bf2f(Wu[idx]);
  } else {
    const float* Wf = (const float*)W;
    for (int idx = tid; idx < F_INN * F_OUTT; idx += 256) Ws[idx] = Wf[idx];
  }
  __syncthreads();
  const int wave = tid >> 6, lane = tid & 63;
  const int row = blockIdx.x * 4 + wave;
  float hr0, hr1, hr2, hr3;
  if (bf16) {
    ushort4 v = ((const ushort4*)((const unsigned short*)h + row * F_INN))[lane];
    hr0 = bf2f(v.x); hr1 = bf2f(v.y); hr2 = bf2f(v.z); hr3 = bf2f(v.w);
  } else {
    float4 v = ((const float4*)((const float*)h + row * F_INN))[lane];
    hr0 = v.x; hr1 = v.y; hr2 = v.z; hr3 = v.w;
  }
  double acc = 0.0;
  #pragma unroll 8
  for (int l = 0; l < 64; l++) {   // k = l*4 + c
    float h0 = bcastf(hr0, l), h1 = bcastf(hr1, l);
    float h2 = bcastf(hr2, l), h3 = bcastf(hr3, l);
    acc += (double)h0 * (double)Ws[(l * 4 + 0) * F_OUTT + lane];
    acc += (double)h1 * (double)Ws[(l * 4 + 1) * F_OUTT + lane];
    acc += (double)h2 * (double)Ws[(l * 4 + 2) * F_OUTT + lane];
    acc += (double)h3 * (double)Ws[(l * 4 + 3) * F_OUTT + lane];
  }
  const float whv = (float)acc;
  g_Wh[row * F_OUTT + lane] = whv;
  float a1, a2;
  if (bf16) {
    a1 = bf2f(((const unsigned short*)a)[lane]);
    a2 = bf2f(((const unsigned short*)a)[F_OUTT + lane]);
  } else {
    a1 = ((const float*)a)[lane];
    a2 = ((const float*)a)[F_OUTT + lane];
  }
  double t1 = (double)whv * (double)a1;
  double t2 = (double)whv * (double)a2;
  #pragma unroll
  for (int off = 32; off > 0; off >>= 1) {
    t1 += __shfl_down(t1, off);
    t2 += __shfl_down(t2, off);
  }
  if (lane == 0) { g_s1[row] = (float)t1; g_s2[row] = (float)t2; }
}

// K2: per-row attention + fused GX. Identical math/order to round 4,
// runtime dtype branch, vectorized w_ih loads.
__global__ __launch_bounds__(256) void k_att(
    const void* __restrict__ adj, const void* __restrict__ w_ih)
{
  const bool bf16 = (g_mode == 1);
  const int i = blockIdx.x, tid = threadIdx.x;
  __shared__ int    nbr[MAXDEG];
  __shared__ float  att_s[MAXDEG];
  __shared__ int    sorted_j[MAXDEG];
  __shared__ double part[4][F_OUTT];
  __shared__ float  wh2row[F_OUTT];
  __shared__ int    cnt;
  if (tid == 0) cnt = 0;
  __syncthreads();
  if (bf16) {
    const uint4* ar = (const uint4*)((const unsigned short*)adj + (size_t)i * N_NODES);
    for (int c = tid; c < N_NODES / 8; c += 256) {   // 8 bf16 per uint4
      uint4 v = ar[c];
      unsigned int w[4] = {v.x, v.y, v.z, v.w};
      #pragma unroll
      for (int k = 0; k < 4; k++) {
        if (w[k] & 0x0000FFFFu) { int p = atomicAdd(&cnt, 1); if (p < MAXDEG) nbr[p] = c*8 + k*2; }
        if (w[k] & 0xFFFF0000u) { int p = atomicAdd(&cnt, 1); if (p < MAXDEG) nbr[p] = c*8 + k*2 + 1; }
      }
    }
  } else {
    const float4* ar = (const float4*)((const float*)adj + (size_t)i * N_NODES);
    for (int c = tid; c < N_NODES / 4; c += 256) {
      float4 v = ar[c];
      if (v.x != 0.0f) { int p = atomicAdd(&cnt, 1); if (p < MAXDEG) nbr[p] = c*4;     }
      if (v.y != 0.0f) { int p = atomicAdd(&cnt, 1); if (p < MAXDEG) nbr[p] = c*4 + 1; }
      if (v.z != 0.0f) { int p = atomicAdd(&cnt, 1); if (p < MAXDEG) nbr[p] = c*4 + 2; }
      if (v.w != 0.0f) { int p = atomicAdd(&cnt, 1); if (p < MAXDEG) nbr[p] = c*4 + 3; }
    }
  }
  __syncthreads();
  const int L = min(cnt, MAXDEG);   // == seq_length[i]
  float ef = -3.0e38f; int jn = 0x7fffffff;
  if (tid < L) {
    jn = nbr[tid];
    float s = g_s1[i] + g_s2[jn];              // fp32 add, like reference
    ef = (s > 0.0f) ? s : 0.2f * s;            // leaky_relu fp32
  }
  float af = 0.0f;
  if (tid < 64) {  // wave 0 holds all neighbor slots (L <= 64)
    float m = ef;
    #pragma unroll
    for (int off = 32; off > 0; off >>= 1) m = fmaxf(m, __shfl_down(m, off));
    m = __shfl(m, 0);
    double p = (tid < L) ? exp((double)(ef - m)) : 0.0;
    double ssum = p;
    #pragma unroll
    for (int off = 32; off > 0; off >>= 1) ssum += __shfl_down(ssum, off);
    ssum = __shfl(ssum, 0);
    af = (float)(p / ssum);
    att_s[tid] = af;
  }
  __syncthreads();
  if (tid < L) {
    int rank = 0;
    for (int q = 0; q < L; q++) {
      float aq = att_s[q]; int jq = nbr[q];
      if (aq > af || (aq == af && jq < jn)) rank++;
    }
    sorted_j[rank] = jn;
  }
  // Wh2 gather split across all 4 waves.
  {
    const int wave = tid >> 6, lane = tid & 63;
    double acc = 0.0;
    for (int q = wave; q < L; q += 4)
      acc += (double)att_s[q] * (double)g_Wh[(size_t)nbr[q] * F_OUTT + lane];
    part[wave][lane] = acc;
  }
  __syncthreads();
  if (tid < MAXDEG)
    g_rev[i * MAXDEG + tid] = (tid < L) ? sorted_j[L - 1 - tid] : 0;
  if (tid < 64)
    wh2row[tid] = (float)(part[0][tid] + part[1][tid] + part[2][tid] + part[3][tid]);
  __syncthreads();
  // Fused GX: gate-row tid: dot(w_ih[tid,:], wh2row), fp64, j ascending.
  {
    double acc = 0.0;
    if (bf16) {
      const uint2* wrow = (const uint2*)((const unsigned short*)w_ih + (size_t)tid * F_OUTT);
      #pragma unroll
      for (int q = 0; q < 16; q++) {   // 4 bf16 per uint2
        uint2 v = wrow[q];
        acc += (double)bf2f((unsigned short)(v.x & 0xFFFFu)) * (double)wh2row[q*4 + 0];
        acc += (double)bf2f((unsigned short)(v.x >> 16))     * (double)wh2row[q*4 + 1];
        acc += (double)bf2f((unsigned short)(v.y & 0xFFFFu)) * (double)wh2row[q*4 + 2];
        acc += (double)bf2f((unsigned short)(v.y >> 16))     * (double)wh2row[q*4 + 3];
      }
    } else {
      const float4* wrow = (const float4*)((const float*)w_ih + (size_t)tid * F_OUTT);
      #pragma unroll
      for (int q = 0; q < 16; q++) {
        float4 v = wrow[q];
        acc += (double)v.x * (double)wh2row[q*4 + 0];
        acc += (double)v.y * (double)wh2row[q*4 + 1];
        acc += (double)v.z * (double)wh2row[q*4 + 2];
        acc += (double)v.w * (double)wh2row[q*4 + 3];
      }
    }
    ((float*)g_GX)[(i * F_OUTT + (tid & 63)) * 4 + (tid >> 6)] = (float)acc;
  }
}

// K4 v3: masked LSTM, one wave = 4 rows, grid 256 blocks (1 wave/SIMD, so
// VGPRs are free up to ~256 — launch_bounds(256,1)).
// Two-phase LDS staging: j=0..31 quads -> LDS -> wr[32] VGPRs, then the SAME
// 32 KB LDS is overwritten with j=32..63 quads (compiler cannot fold wr back
// to LDS). j=32..63 consumed via a rotating 4-quad prefetch so ds_read
// latency hides behind FMAs. gx prefetch unconditional as in round 4.
// Arithmetic order identical to round 4 -> bit-identical output.
__global__ __launch_bounds__(256, 1) void k_lstm(
    const void* __restrict__ w_hh, const void* __restrict__ b_ih,
    const void* __restrict__ b_hh, const int* __restrict__ seq,
    void* __restrict__ out)
{
  const bool bf16 = (g_mode == 1);
  __shared__ float4 whq[32 * 64];   // 32 KB
  float* wf = (float*)whq;
  const int tid = threadIdx.x;
  const int wave = tid >> 6, lane = tid & 63;

  // phase 1: stage j=0..31 quads (transposed): wf[(j*64+d)*4+g] = w_hh[g*64+d][j]
  if (bf16) {
    const unsigned short* wh = (const unsigned short*)w_hh;
    for (int idx = tid; idx < 256 * 32; idx += 256) {
      int row = idx >> 5, j = idx & 31;
      wf[(j * 64 + (row & 63)) * 4 + (row >> 6)] = bf2f(wh[row * 64 + j]);
    }
  } else {
    const float* wh = (const float*)w_hh;
    for (int idx = tid; idx < 256 * 32; idx += 256) {
      int row = idx >> 5, j = idx & 31;
      wf[(j * 64 + (row & 63)) * 4 + (row >> 6)] = wh[row * 64 + j];
    }
  }
  __syncthreads();
  float4 wr[32];
  #pragma unroll
  for (int j = 0; j < 32; j++) wr[j] = whq[j * 64 + lane];
  __syncthreads();
  // phase 2: overwrite LDS with j=32..63 quads
  if (bf16) {
    const unsigned short* wh = (const unsigned short*)w_hh;
    for (int idx = tid; idx < 256 * 32; idx += 256) {
      int row = idx >> 5, j = (idx & 31) + 32;
      wf[((j - 32) * 64 + (row & 63)) * 4 + (row >> 6)] = bf2f(wh[row * 64 + j]);
    }
  } else {
    const float* wh = (const float*)w_hh;
    for (int idx = tid; idx < 256 * 32; idx += 256) {
      int row = idx >> 5, j = (idx & 31) + 32;
      wf[((j - 32) * 64 + (row & 63)) * 4 + (row >> 6)] = wh[row * 64 + j];
    }
  }
  __syncthreads();

  const int base = (blockIdx.x * 4 + wave) * 4;
  int rows[4], Ls[4], rbase[4];
  #pragma unroll
  for (int r = 0; r < 4; r++) {
    rows[r]  = g_perm[base + r] & (N_NODES - 1);
    Ls[r]    = min(max(seq[rows[r]], 0), MAXDEG);
    rbase[r] = rows[r] * MAXDEG;
  }
  const int Lmax = max(max(Ls[0], Ls[1]), max(Ls[2], Ls[3]));
  float bsum[4];
  if (bf16) {
    #pragma unroll
    for (int g = 0; g < 4; g++)
      bsum[g] = bf2f(((const unsigned short*)b_ih)[g * 64 + lane]) +
                bf2f(((const unsigned short*)b_hh)[g * 64 + lane]);
  } else {
    #pragma unroll
    for (int g = 0; g < 4; g++)
      bsum[g] = ((const float*)b_ih)[g * 64 + lane] + ((const float*)b_hh)[g * 64 + lane];
  }

  float hcur[4] = {0.f,0.f,0.f,0.f}, ccur[4] = {0.f,0.f,0.f,0.f};
  float4 gx[4];
  #pragma unroll
  for (int r = 0; r < 4; r++) {
    int src0 = g_rev[rbase[r]] & (N_NODES - 1);
    gx[r] = g_GX[src0 * F_OUTT + lane];
  }

  for (int t = 0; t < Lmax; t++) {
    float acc[4][4];
    #pragma unroll
    for (int r = 0; r < 4; r++) {
      acc[r][0] = bsum[0] + gx[r].x; acc[r][1] = bsum[1] + gx[r].y;
      acc[r][2] = bsum[2] + gx[r].z; acc[r][3] = bsum[3] + gx[r].w;
    }
    // prefetch next step's gx (unconditional) straight into gx regs
    {
      const int tn = (t + 1) & (MAXDEG - 1);
      #pragma unroll
      for (int r = 0; r < 4; r++) {
        int srcn = g_rev[rbase[r] + tn] & (N_NODES - 1);
        gx[r] = g_GX[srcn * F_OUTT + lane];
      }
    }
    // issue LDS group 0 (j=32..35) ahead of the register FMAs
    float4 p0 = whq[0 * 64 + lane], p1 = whq[1 * 64 + lane];
    float4 p2 = whq[2 * 64 + lane], p3 = whq[3 * 64 + lane];
    // j = 0..31 from registers
    #pragma unroll
    for (int j = 0; j < 32; j++) {
      float4 wv = wr[j];
      #pragma unroll
      for (int r = 0; r < 4; r++) {
        float hv = bcastf(hcur[r], j);
        acc[r][0] = fmaf(wv.x, hv, acc[r][0]);
        acc[r][1] = fmaf(wv.y, hv, acc[r][1]);
        acc[r][2] = fmaf(wv.z, hv, acc[r][2]);
        acc[r][3] = fmaf(wv.w, hv, acc[r][3]);
      }
    }
    // j = 32..63 from LDS, rotating 4-quad prefetch
    #pragma unroll
    for (int grp = 0; grp < 8; grp++) {
      float4 n0, n1, n2, n3;
      if (grp < 7) {
        n0 = whq[((grp + 1) * 4 + 0) * 64 + lane];
        n1 = whq[((grp + 1) * 4 + 1) * 64 + lane];
        n2 = whq[((grp + 1) * 4 + 2) * 64 + lane];
        n3 = whq[((grp + 1) * 4 + 3) * 64 + lane];
      }
      #pragma unroll
      for (int u = 0; u < 4; u++) {
        const int j = 32 + grp * 4 + u;
        float4 wv = (u == 0) ? p0 : (u == 1) ? p1 : (u == 2) ? p2 : p3;
        #pragma unroll
        for (int r = 0; r < 4; r++) {
          float hv = bcastf(hcur[r], j);
          acc[r][0] = fmaf(wv.x, hv, acc[r][0]);
          acc[r][1] = fmaf(wv.y, hv, acc[r][1]);
          acc[r][2] = fmaf(wv.z, hv, acc[r][2]);
          acc[r][3] = fmaf(wv.w, hv, acc[r][3]);
        }
      }
      if (grp < 7) { p0 = n0; p1 = n1; p2 = n2; p3 = n3; }
    }
    #pragma unroll
    for (int r = 0; r < 4; r++) {
      float ig = sigm(acc[r][0]);
      float fg = sigm(acc[r][1]);
      float gg = tanh_fast(acc[r][2]);
      float og = sigm(acc[r][3]);
      float cn = fg * ccur[r] + ig * gg;
      float hn = og * tanh_fast(cn);
      bool live = (t < Ls[r]);
      ccur[r] = live ? cn : ccur[r];
      hcur[r] = live ? hn : hcur[r];
    }
  }
  #pragma unroll
  for (int r = 0; r < 4; r++) {
    if (bf16) ((__hip_bfloat16*)out)[rows[r] * HID + lane] = __float2bfloat16(hcur[r]);
    else      ((float*)out)[rows[r] * HID + lane] = hcur[r];
  }
}

extern "C" void kernel_launch(void* const* d_in, const int* in_sizes, int n_in,
                              void* d_out, int out_size, void* d_ws, size_t ws_size,
                              hipStream_t stream) {
  (void)in_sizes; (void)n_in; (void)out_size; (void)d_ws; (void)ws_size;
  const void* h    = d_in[0];
  const void* adj  = d_in[1];
  const int*  seq  = (const int*)d_in[2];
  const void* W    = d_in[3];
  const void* a    = d_in[4];
  const void* w_ih = d_in[5];
  const void* w_hh = d_in[6];
  const void* b_ih = d_in[7];
  const void* b_hh = d_in[8];

  k_setup<<<1,            256, 0, stream>>>((const unsigned int*)adj, seq);
  k_wh   <<<N_NODES / 4,  256, 0, stream>>>(h, W, a);
  k_att  <<<N_NODES,      256, 0, stream>>>(adj, w_ih);
  k_lstm <<<N_NODES / 16, 256, 0, stream>>>(w_hh, b_ih, b_hh, seq, d_out);
}

// Round 6
// 371.187 us; speedup vs baseline: 1.6680x; 1.6680x over previous
//
#include <hip/hip_runtime.h>
#include <hip/hip_bf16.h>
#include <math.h>

#define N_NODES 4096
#define F_INN   256
#define F_OUTT  64
#define HID     64
#define MAXDEG  64

// Scratch in device globals (no ws_size dependence). Fully rewritten each call.
__device__ int    g_mode;                    // 0 = fp32 inputs, 1 = bf16 inputs
__device__ int    g_anyArr[64];              // per-block detector flags
__device__ float  g_Wh [N_NODES * F_OUTT];
__device__ float  g_s1 [N_NODES];
__device__ float  g_s2 [N_NODES];
__device__ int    g_rev[N_NODES * MAXDEG];
__device__ int    g_perm[N_NODES];
__device__ float4 g_GX [N_NODES * F_OUTT];   // per (node, unit): quad {i,f,g,o}

__device__ __forceinline__ float bf2f(unsigned short u) {
  union { unsigned int i; float f; } v; v.i = ((unsigned int)u) << 16; return v.f;
}

__device__ __forceinline__ float bcastf(float v, int l) {
#if __has_builtin(__builtin_amdgcn_readlane)
  return __int_as_float(__builtin_amdgcn_readlane(__float_as_int(v), l));
#else
  return __shfl(v, l);
#endif
}

__device__ __forceinline__ float sigm(float x) { return 1.f / (1.f + __expf(-x)); }
__device__ __forceinline__ float tanh_fast(float x) { return 1.f - 2.f / (1.f + __expf(2.f * x)); }

// D0: parallel dtype detector. 64 blocks x 256 threads x one uint4 each =
// 65536 words (8 fp32 adj rows / 16 bf16 rows; bf16 => ~256 nonzero
// low-halves expected -> detection certain). Flags always written (no
// cross-call state, no init race).
__global__ __launch_bounds__(256) void k_detect(const unsigned int* __restrict__ aw) {
  __shared__ int any;
  if (threadIdx.x == 0) any = 0;
  __syncthreads();
  const uint4 v = ((const uint4*)aw)[blockIdx.x * 256 + threadIdx.x];
  int loc = (int)((v.x & 0xFFFFu) | (v.y & 0xFFFFu) | (v.z & 0xFFFFu) | (v.w & 0xFFFFu));
  if (loc) atomicOr(&any, 1);
  __syncthreads();
  if (threadIdx.x == 0) g_anyArr[blockIdx.x] = any;
}

// S1: reduce detector flags -> g_mode, then counting sort by seq_length
// descending (scheduling only; any permutation is correct).
__global__ __launch_bounds__(256) void k_sort(const int* __restrict__ seq) {
  __shared__ int hist[MAXDEG + 1];
  __shared__ int offs[MAXDEG + 1];
  const int tid = threadIdx.x;
  if (tid <= MAXDEG) hist[tid] = 0;
  __syncthreads();
  if (tid == 0) {
    int any = 0;
    for (int b = 0; b < 64; b++) any |= g_anyArr[b];
    g_mode = any ? 1 : 0;
  }
  for (int i = tid; i < N_NODES; i += 256)
    atomicAdd(&hist[min(max(seq[i], 0), MAXDEG)], 1);
  __syncthreads();
  if (tid == 0) {
    int run = 0;
    for (int L = MAXDEG; L >= 0; L--) { offs[L] = run; run += hist[L]; }
  }
  __syncthreads();
  for (int i = tid; i < N_NODES; i += 256) {
    int p = atomicAdd(&offs[min(max(seq[i], 0), MAXDEG)], 1);
    g_perm[p] = i;
  }
}

// K1: Wh = h @ W (fp64 accumulate -> fp32), s1 = Wh@a1, s2 = Wh@a2 (fp64).
// Vectorized W staging; compute order identical to rounds 4/5.
__global__ __launch_bounds__(256) void k_wh(
    const void* __restrict__ h, const void* __restrict__ W, const void* __restrict__ a)
{
  const bool bf16 = (g_mode == 1);
  __shared__ float Ws[F_INN * F_OUTT];   // 64 KB
  const int tid = threadIdx.x;
  if (bf16) {
    const ushort4* Wu = (const ushort4*)W;
    for (int v = tid; v < F_INN * F_OUTT / 4; v += 256) {
      ushort4 u = Wu[v];
      ((float4*)Ws)[v] = make_float4(bf2f(u.x), bf2f(u.y), bf2f(u.z), bf2f(u.w));
    }
  } else {
    const float4* Wf = (const float4*)W;
    for (int v = tid; v < F_INN * F_OUTT / 4; v += 256) ((float4*)Ws)[v] = Wf[v];
  }
  __syncthreads();
  const int wave = tid >> 6, lane = tid & 63;
  const int row = blockIdx.x * 4 + wave;
  float hr0, hr1, hr2, hr3;
  if (bf16) {
    ushort4 v = ((const ushort4*)((const unsigned short*)h + row * F_INN))[lane];
    hr0 = bf2f(v.x); hr1 = bf2f(v.y); hr2 = bf2f(v.z); hr3 = bf2f(v.w);
  } else {
    float4 v = ((const float4*)((const float*)h + row * F_INN))[lane];
    hr0 = v.x; hr1 = v.y; hr2 = v.z; hr3 = v.w;
  }
  double acc = 0.0;
  #pragma unroll 8
  for (int l = 0; l < 64; l++) {   // k = l*4 + c
    float h0 = bcastf(hr0, l), h1 = bcastf(hr1, l);
    float h2 = bcastf(hr2, l), h3 = bcastf(hr3, l);
    acc += (double)h0 * (double)Ws[(l * 4 + 0) * F_OUTT + lane];
    acc += (double)h1 * (double)Ws[(l * 4 + 1) * F_OUTT + lane];
    acc += (double)h2 * (double)Ws[(l * 4 + 2) * F_OUTT + lane];
    acc += (double)h3 * (double)Ws[(l * 4 + 3) * F_OUTT + lane];
  }
  const float whv = (float)acc;
  g_Wh[row * F_OUTT + lane] = whv;
  float a1, a2;
  if (bf16) {
    a1 = bf2f(((const unsigned short*)a)[lane]);
    a2 = bf2f(((const unsigned short*)a)[F_OUTT + lane]);
  } else {
    a1 = ((const float*)a)[lane];
    a2 = ((const float*)a)[F_OUTT + lane];
  }
  double t1 = (double)whv * (double)a1;
  double t2 = (double)whv * (double)a2;
  #pragma unroll
  for (int off = 32; off > 0; off >>= 1) {
    t1 += __shfl_down(t1, off);
    t2 += __shfl_down(t2, off);
  }
  if (lane == 0) { g_s1[row] = (float)t1; g_s2[row] = (float)t2; }
}

// K2: per-row attention + fused GX. Byte-identical logic to round 5.
__global__ __launch_bounds__(256) void k_att(
    const void* __restrict__ adj, const void* __restrict__ w_ih)
{
  const bool bf16 = (g_mode == 1);
  const int i = blockIdx.x, tid = threadIdx.x;
  __shared__ int    nbr[MAXDEG];
  __shared__ float  att_s[MAXDEG];
  __shared__ int    sorted_j[MAXDEG];
  __shared__ double part[4][F_OUTT];
  __shared__ float  wh2row[F_OUTT];
  __shared__ int    cnt;
  if (tid == 0) cnt = 0;
  __syncthreads();
  if (bf16) {
    const uint4* ar = (const uint4*)((const unsigned short*)adj + (size_t)i * N_NODES);
    for (int c = tid; c < N_NODES / 8; c += 256) {   // 8 bf16 per uint4
      uint4 v = ar[c];
      unsigned int w[4] = {v.x, v.y, v.z, v.w};
      #pragma unroll
      for (int k = 0; k < 4; k++) {
        if (w[k] & 0x0000FFFFu) { int p = atomicAdd(&cnt, 1); if (p < MAXDEG) nbr[p] = c*8 + k*2; }
        if (w[k] & 0xFFFF0000u) { int p = atomicAdd(&cnt, 1); if (p < MAXDEG) nbr[p] = c*8 + k*2 + 1; }
      }
    }
  } else {
    const float4* ar = (const float4*)((const float*)adj + (size_t)i * N_NODES);
    for (int c = tid; c < N_NODES / 4; c += 256) {
      float4 v = ar[c];
      if (v.x != 0.0f) { int p = atomicAdd(&cnt, 1); if (p < MAXDEG) nbr[p] = c*4;     }
      if (v.y != 0.0f) { int p = atomicAdd(&cnt, 1); if (p < MAXDEG) nbr[p] = c*4 + 1; }
      if (v.z != 0.0f) { int p = atomicAdd(&cnt, 1); if (p < MAXDEG) nbr[p] = c*4 + 2; }
      if (v.w != 0.0f) { int p = atomicAdd(&cnt, 1); if (p < MAXDEG) nbr[p] = c*4 + 3; }
    }
  }
  __syncthreads();
  const int L = min(cnt, MAXDEG);   // == seq_length[i]
  float ef = -3.0e38f; int jn = 0x7fffffff;
  if (tid < L) {
    jn = nbr[tid];
    float s = g_s1[i] + g_s2[jn];              // fp32 add, like reference
    ef = (s > 0.0f) ? s : 0.2f * s;            // leaky_relu fp32
  }
  float af = 0.0f;
  if (tid < 64) {  // wave 0 holds all neighbor slots (L <= 64)
    float m = ef;
    #pragma unroll
    for (int off = 32; off > 0; off >>= 1) m = fmaxf(m, __shfl_down(m, off));
    m = __shfl(m, 0);
    double p = (tid < L) ? exp((double)(ef - m)) : 0.0;
    double ssum = p;
    #pragma unroll
    for (int off = 32; off > 0; off >>= 1) ssum += __shfl_down(ssum, off);
    ssum = __shfl(ssum, 0);
    af = (float)(p / ssum);
    att_s[tid] = af;
  }
  __syncthreads();
  if (tid < L) {
    int rank = 0;
    for (int q = 0; q < L; q++) {
      float aq = att_s[q]; int jq = nbr[q];
      if (aq > af || (aq == af && jq < jn)) rank++;
    }
    sorted_j[rank] = jn;
  }
  // Wh2 gather split across all 4 waves.
  {
    const int wave = tid >> 6, lane = tid & 63;
    double acc = 0.0;
    for (int q = wave; q < L; q += 4)
      acc += (double)att_s[q] * (double)g_Wh[(size_t)nbr[q] * F_OUTT + lane];
    part[wave][lane] = acc;
  }
  __syncthreads();
  if (tid < MAXDEG)
    g_rev[i * MAXDEG + tid] = (tid < L) ? sorted_j[L - 1 - tid] : 0;
  if (tid < 64)
    wh2row[tid] = (float)(part[0][tid] + part[1][tid] + part[2][tid] + part[3][tid]);
  __syncthreads();
  // Fused GX: gate-row tid: dot(w_ih[tid,:], wh2row), fp64, j ascending.
  {
    double acc = 0.0;
    if (bf16) {
      const uint2* wrow = (const uint2*)((const unsigned short*)w_ih + (size_t)tid * F_OUTT);
      #pragma unroll
      for (int q = 0; q < 16; q++) {   // 4 bf16 per uint2
        uint2 v = wrow[q];
        acc += (double)bf2f((unsigned short)(v.x & 0xFFFFu)) * (double)wh2row[q*4 + 0];
        acc += (double)bf2f((unsigned short)(v.x >> 16))     * (double)wh2row[q*4 + 1];
        acc += (double)bf2f((unsigned short)(v.y & 0xFFFFu)) * (double)wh2row[q*4 + 2];
        acc += (double)bf2f((unsigned short)(v.y >> 16))     * (double)wh2row[q*4 + 3];
      }
    } else {
      const float4* wrow = (const float4*)((const float*)w_ih + (size_t)tid * F_OUTT);
      #pragma unroll
      for (int q = 0; q < 16; q++) {
        float4 v = wrow[q];
        acc += (double)v.x * (double)wh2row[q*4 + 0];
        acc += (double)v.y * (double)wh2row[q*4 + 1];
        acc += (double)v.z * (double)wh2row[q*4 + 2];
        acc += (double)v.w * (double)wh2row[q*4 + 3];
      }
    }
    ((float*)g_GX)[(i * F_OUTT + (tid & 63)) * 4 + (tid >> 6)] = (float)acc;
  }
}

// K4 v4: masked LSTM. Revert to the r4 all-LDS weight scheme (the r5
// register-pinning spilled to AGPR = doubled VALU work), split as
// 2 rows/wave x 8 waves (512-thread block, grid 256): 2 waves/SIMD
// co-resident so FMAs of one wave hide the other's ds_read/gather latency.
// Per-row arithmetic order identical to r4/r5 -> bit-identical output.
__global__ __launch_bounds__(512, 2) void k_lstm(
    const void* __restrict__ w_hh, const void* __restrict__ b_ih,
    const void* __restrict__ b_hh, const int* __restrict__ seq,
    void* __restrict__ out)
{
  const bool bf16 = (g_mode == 1);
  __shared__ float4 whq[64 * 64];   // 64 KB: whq[j*64+d] = {w_hh[g*64+d][j]}g
  float* wf = (float*)whq;
  const int tid = threadIdx.x;
  // staging: thread u handles w_hh[row][j4..j4+3] (vector load, 4 ds_writes)
  for (int u = tid; u < 4096; u += 512) {
    const int row = u >> 4;            // gate row = g*64+d
    const int j4  = (u & 15) * 4;
    const int g = row >> 6, d = row & 63;
    float f0, f1, f2, f3;
    if (bf16) {
      ushort4 v = ((const ushort4*)w_hh)[u];
      f0 = bf2f(v.x); f1 = bf2f(v.y); f2 = bf2f(v.z); f3 = bf2f(v.w);
    } else {
      float4 v = ((const float4*)w_hh)[u];
      f0 = v.x; f1 = v.y; f2 = v.z; f3 = v.w;
    }
    wf[((j4 + 0) * 64 + d) * 4 + g] = f0;
    wf[((j4 + 1) * 64 + d) * 4 + g] = f1;
    wf[((j4 + 2) * 64 + d) * 4 + g] = f2;
    wf[((j4 + 3) * 64 + d) * 4 + g] = f3;
  }
  __syncthreads();
  const int wave = tid >> 6, lane = tid & 63;
  const int base = (blockIdx.x * 8 + wave) * 2;
  int rows[2], Ls[2], rbase[2];
  #pragma unroll
  for (int r = 0; r < 2; r++) {
    rows[r]  = g_perm[base + r] & (N_NODES - 1);
    Ls[r]    = min(max(seq[rows[r]], 0), MAXDEG);
    rbase[r] = rows[r] * MAXDEG;
  }
  const int Lmax = max(Ls[0], Ls[1]);
  float bsum[4];
  if (bf16) {
    #pragma unroll
    for (int g = 0; g < 4; g++)
      bsum[g] = bf2f(((const unsigned short*)b_ih)[g * 64 + lane]) +
                bf2f(((const unsigned short*)b_hh)[g * 64 + lane]);
  } else {
    #pragma unroll
    for (int g = 0; g < 4; g++)
      bsum[g] = ((const float*)b_ih)[g * 64 + lane] + ((const float*)b_hh)[g * 64 + lane];
  }

  float hcur[2] = {0.f, 0.f}, ccur[2] = {0.f, 0.f};
  float4 gx[2];
  #pragma unroll
  for (int r = 0; r < 2; r++) {
    int src0 = g_rev[rbase[r]] & (N_NODES - 1);
    gx[r] = g_GX[src0 * F_OUTT + lane];
  }

  for (int t = 0; t < Lmax; t++) {
    // prefetch next step's gx (unconditional; masked steps ignore it)
    float4 gxn[2];
    {
      const int tn = (t + 1) & (MAXDEG - 1);
      #pragma unroll
      for (int r = 0; r < 2; r++) {
        int srcn = g_rev[rbase[r] + tn] & (N_NODES - 1);
        gxn[r] = g_GX[srcn * F_OUTT + lane];
      }
    }
    float acc[2][4];
    #pragma unroll
    for (int r = 0; r < 2; r++) {
      acc[r][0] = bsum[0] + gx[r].x; acc[r][1] = bsum[1] + gx[r].y;
      acc[r][2] = bsum[2] + gx[r].z; acc[r][3] = bsum[3] + gx[r].w;
    }
    #pragma unroll 16
    for (int j = 0; j < 64; j++) {
      float4 wv = whq[j * 64 + lane];
      #pragma unroll
      for (int r = 0; r < 2; r++) {
        float hv = bcastf(hcur[r], j);
        acc[r][0] = fmaf(wv.x, hv, acc[r][0]);
        acc[r][1] = fmaf(wv.y, hv, acc[r][1]);
        acc[r][2] = fmaf(wv.z, hv, acc[r][2]);
        acc[r][3] = fmaf(wv.w, hv, acc[r][3]);
      }
    }
    #pragma unroll
    for (int r = 0; r < 2; r++) {
      float ig = sigm(acc[r][0]);
      float fg = sigm(acc[r][1]);
      float gg = tanh_fast(acc[r][2]);
      float og = sigm(acc[r][3]);
      float cn = fg * ccur[r] + ig * gg;
      float hn = og * tanh_fast(cn);
      bool live = (t < Ls[r]);
      ccur[r] = live ? cn : ccur[r];
      hcur[r] = live ? hn : hcur[r];
      gx[r] = gxn[r];
    }
  }
  #pragma unroll
  for (int r = 0; r < 2; r++) {
    if (bf16) ((__hip_bfloat16*)out)[rows[r] * HID + lane] = __float2bfloat16(hcur[r]);
    else      ((float*)out)[rows[r] * HID + lane] = hcur[r];
  }
}

extern "C" void kernel_launch(void* const* d_in, const int* in_sizes, int n_in,
                              void* d_out, int out_size, void* d_ws, size_t ws_size,
                              hipStream_t stream) {
  (void)in_sizes; (void)n_in; (void)out_size; (void)d_ws; (void)ws_size;
  const void* h    = d_in[0];
  const void* adj  = d_in[1];
  const int*  seq  = (const int*)d_in[2];
  const void* W    = d_in[3];
  const void* a    = d_in[4];
  const void* w_ih = d_in[5];
  const void* w_hh = d_in[6];
  const void* b_ih = d_in[7];
  const void* b_hh = d_in[8];

  k_detect<<<64,           256, 0, stream>>>((const unsigned int*)adj);
  k_sort  <<<1,            256, 0, stream>>>(seq);
  k_wh    <<<N_NODES / 4,  256, 0, stream>>>(h, W, a);
  k_att   <<<N_NODES,      256, 0, stream>>>(adj, w_ih);
  k_lstm  <<<N_NODES / 16, 512, 0, stream>>>(w_hh, b_ih, b_hh, seq, d_out);
}